// Round 6
// baseline (21.879 us; speedup 1.0000x reference)
//
#include <hip/hip_runtime.h>
#include <hip/hip_bf16.h>

// B=512, N=64, D=128, 4 edge types.
// out[b] = softmax_j(select_k(leakyrelu((h*a_k) @ h^T), adj)) @ h
// Grid 256, 512-thr blocks, 2 batches/block, wave-specialized pipeline:
//   P1: stage b0 (all)          | issue ALL global loads at top
//   P2: E=eGEMM+SM(b0)          | P=write b1 to LDS
//   P3: E=eGEMM+SM(b1)          | P=PV(b0)
//   P4: all waves split PV(b1)

#define NN 64
#define ND 128
#define HS 136   // h_lds row stride (128 + 8 pad)
#define AS 72    // alpha row stride

typedef __bf16 bf16x8 __attribute__((ext_vector_type(8)));
typedef __bf16 bf16x4 __attribute__((ext_vector_type(4)));
typedef float  f32x4  __attribute__((ext_vector_type(4)));

__device__ __forceinline__ void egemm_softmax(
    const __bf16* __restrict__ h, const float* __restrict__ a_lds,
    const int (*adjv)[4], __bf16* __restrict__ al, float* __restrict__ invl,
    int w, int l, int g, int g8)
{
    const int i0   = w * 16 + (g << 2);
    const int irow = w * 16 + (l & 15);
    f32x4 acc[4][4];   // [ct][k]
    #pragma unroll
    for (int ct = 0; ct < 4; ++ct)
        #pragma unroll
        for (int k = 0; k < 4; ++k)
            acc[ct][k] = (f32x4){0.f, 0.f, 0.f, 0.f};

    #pragma unroll
    for (int kk = 0; kk < 4; ++kk) {
        int d0 = kk * 32 + g8;
        bf16x8 hf = *(const bf16x8*)&h[irow * HS + d0];
        float hff[8];
        #pragma unroll
        for (int e = 0; e < 8; ++e) hff[e] = (float)hf[e];
        bf16x8 hk[4];
        #pragma unroll
        for (int k = 0; k < 4; ++k) {
            float4 alo = *(const float4*)&a_lds[k * ND + d0];
            float4 ahi = *(const float4*)&a_lds[k * ND + d0 + 4];
            bf16x8 r;
            r[0] = (__bf16)(hff[0] * alo.x); r[1] = (__bf16)(hff[1] * alo.y);
            r[2] = (__bf16)(hff[2] * alo.z); r[3] = (__bf16)(hff[3] * alo.w);
            r[4] = (__bf16)(hff[4] * ahi.x); r[5] = (__bf16)(hff[5] * ahi.y);
            r[6] = (__bf16)(hff[6] * ahi.z); r[7] = (__bf16)(hff[7] * ahi.w);
            hk[k] = r;
        }
        bf16x8 bfr[4];
        #pragma unroll
        for (int ct = 0; ct < 4; ++ct)
            bfr[ct] = *(const bf16x8*)&h[(ct * 16 + (l & 15)) * HS + d0];
        #pragma unroll
        for (int ct = 0; ct < 4; ++ct)
            #pragma unroll
            for (int k = 0; k < 4; ++k)
                acc[ct][k] = __builtin_amdgcn_mfma_f32_16x16x32_bf16(hk[k], bfr[ct], acc[ct][k], 0, 0, 0);
    }

    float sel[4][4];
    #pragma unroll
    for (int ct = 0; ct < 4; ++ct)
        #pragma unroll
        for (int r = 0; r < 4; ++r) {
            int av = adjv[ct][r];
            float e0 = fmaxf(acc[ct][0][r], 0.2f * acc[ct][0][r]);
            float e1 = fmaxf(acc[ct][1][r], 0.2f * acc[ct][1][r]);
            float e2 = fmaxf(acc[ct][2][r], 0.2f * acc[ct][2][r]);
            float e3 = fmaxf(acc[ct][3][r], 0.2f * acc[ct][3][r]);
            sel[ct][r] = av == 1 ? e0 : av == 2 ? e1 : av == 3 ? e2 : av == 4 ? e3 : -9.0e15f;
        }

    #pragma unroll
    for (int r = 0; r < 4; ++r) {
        float m = fmaxf(fmaxf(sel[0][r], sel[1][r]), fmaxf(sel[2][r], sel[3][r]));
        m = fmaxf(m, __shfl_xor(m, 1));
        m = fmaxf(m, __shfl_xor(m, 2));
        m = fmaxf(m, __shfl_xor(m, 4));
        m = fmaxf(m, __shfl_xor(m, 8));
        float p0 = __expf(sel[0][r] - m);
        float p1 = __expf(sel[1][r] - m);
        float p2 = __expf(sel[2][r] - m);
        float p3 = __expf(sel[3][r] - m);
        float s = p0 + p1 + p2 + p3;
        s += __shfl_xor(s, 1);
        s += __shfl_xor(s, 2);
        s += __shfl_xor(s, 4);
        s += __shfl_xor(s, 8);
        int i = i0 + r;
        al[i * AS +  0 + (l & 15)] = (__bf16)p0;   // unnormalized; inv applied at PV
        al[i * AS + 16 + (l & 15)] = (__bf16)p1;
        al[i * AS + 32 + (l & 15)] = (__bf16)p2;
        al[i * AS + 48 + (l & 15)] = (__bf16)p3;
        if ((l & 15) == 0) invl[i] = 1.0f / s;
    }
}

template<int NDT>
__device__ __forceinline__ void pv_phase(
    const __bf16* __restrict__ htr, const __bf16* __restrict__ al,
    const float* __restrict__ invl, float* __restrict__ outb,
    int itile, int dt0, int l, int g, int g8)
{
    const int ia = itile * 16 + (l & 15);
    bf16x8 pB0 = *(const bf16x8*)&al[ia * AS + g8];
    bf16x8 pB1 = *(const bf16x8*)&al[ia * AS + 32 + g8];
    float invr = invl[ia];
    unsigned trb = (unsigned)(unsigned long long)htr
                 + (unsigned)(((l & 15) << 3) + (g << 8));
    #pragma unroll
    for (int q = 0; q < NDT; ++q) {
        int dt = dt0 + q;
        unsigned ab = trb + dt * 2048;
        bf16x4 r0, r1, r2, r3;
        asm volatile("ds_read_b64_tr_b16 %0, %1"             : "=v"(r0) : "v"(ab));
        asm volatile("ds_read_b64_tr_b16 %0, %1 offset:128"  : "=v"(r1) : "v"(ab));
        asm volatile("ds_read_b64_tr_b16 %0, %1 offset:1024" : "=v"(r2) : "v"(ab));
        asm volatile("ds_read_b64_tr_b16 %0, %1 offset:1152" : "=v"(r3) : "v"(ab));
        asm volatile("s_waitcnt lgkmcnt(0)" ::: "memory");
        __builtin_amdgcn_sched_barrier(0);
        bf16x8 A0 = __builtin_shufflevector(r0, r1, 0, 1, 2, 3, 4, 5, 6, 7);
        bf16x8 A1 = __builtin_shufflevector(r2, r3, 0, 1, 2, 3, 4, 5, 6, 7);
        f32x4 o = {0.f, 0.f, 0.f, 0.f};
        o = __builtin_amdgcn_mfma_f32_16x16x32_bf16(A0, pB0, o, 0, 0, 0);
        o = __builtin_amdgcn_mfma_f32_16x16x32_bf16(A1, pB1, o, 0, 0, 0);
        float4 st = { o[0] * invr, o[1] * invr, o[2] * invr, o[3] * invr };
        *(float4*)&outb[ia * ND + dt * 16 + (g << 2)] = st;
    }
}

__global__ __launch_bounds__(512, 1)
void gat_kernel(const float* __restrict__ hidden,
                const int*   __restrict__ adj,
                const float* __restrict__ a,
                float*       __restrict__ out)
{
    __shared__ __bf16 h_lds[2][NN * HS];     // 2 x 17408 B
    __shared__ __bf16 h_tr[2][8 * NN * 16];  // 2 x 16384 B
    __shared__ __bf16 al_lds[2][NN * AS];    // 2 x  9216 B
    __shared__ float  inv_lds[2][NN];        // 2 x   256 B
    __shared__ float  a_lds[4 * ND];         //      2048 B  -> 88576 B total

    const int t = threadIdx.x;
    const int l = t & 63;
    const int w = t >> 6;              // 0..7
    const int g  = l >> 4;
    const int g8 = g << 3;
    const size_t b0 = 2 * (size_t)blockIdx.x;
    const size_t b1 = b0 + 1;

    // ================= issue ALL global loads up front =================
    const float4* hin0 = (const float4*)(hidden + b0 * NN * ND);
    const float4* hin1 = (const float4*)(hidden + b1 * NN * ND);

    // b0 staging share (all 8 waves, 4 float4 each)
    float4 sv[4];
    int srow[4], sf4[4];
    #pragma unroll
    for (int s = 0; s < 4; ++s) {
        int cb = (w & 3) | ((s & 1) << 2);          // 0..7
        int rb = (w >> 2) | ((s >> 1) << 1);        // 0..3
        srow[s] = ((l >> 2) & 15) | (rb << 4);
        sf4[s]  = (l & 3) | (cb << 2);
        sv[s] = hin0[srow[s] * 32 + sf4[s]];
    }
    // b1 staging (P-waves only, 8 float4 each)
    float4 pv[8];
    int prow[8], pf4[8];
    if (w >= 4) {
        #pragma unroll
        for (int s = 0; s < 8; ++s) {
            int cb = ((w - 4) & 3) | ((s & 1) << 2);
            int rb = s >> 1;
            prow[s] = ((l >> 2) & 15) | (rb << 4);
            pf4[s]  = (l & 3) | (cb << 2);
            pv[s] = hin1[prow[s] * 32 + pf4[s]];
        }
    }
    // adj for both batches (E-waves only)
    int adjv0[4][4], adjv1[4][4];
    if (w < 4) {
        const int i0 = w * 16 + (g << 2);
        const int* a0 = adj + b0 * NN * NN;
        const int* a1 = adj + b1 * NN * NN;
        #pragma unroll
        for (int ct = 0; ct < 4; ++ct)
            #pragma unroll
            for (int r = 0; r < 4; ++r) {
                adjv0[ct][r] = a0[(i0 + r) * NN + ct * 16 + (l & 15)];
                adjv1[ct][r] = a1[(i0 + r) * NN + ct * 16 + (l & 15)];
            }
    }
    a_lds[t] = a[t];   // 512 floats, one per thread

    // ================= P1: write b0 to LDS =================
    #pragma unroll
    for (int s = 0; s < 4; ++s) {
        float4 v = sv[s];
        bf16x4 pk = { (__bf16)v.x, (__bf16)v.y, (__bf16)v.z, (__bf16)v.w };
        int c4 = sf4[s] << 2;
        *(bf16x4*)&h_lds[0][srow[s] * HS + c4] = pk;
        *(bf16x4*)&h_tr[0][((c4 >> 4) << 10) + (srow[s] << 4) + (c4 & 15)] = pk;
    }
    __syncthreads();

    // ================= P2: E=eGEMM+SM(b0) | P=write b1 =================
    if (w < 4) {
        egemm_softmax(h_lds[0], a_lds, adjv0, al_lds[0], inv_lds[0], w, l, g, g8);
    } else {
        #pragma unroll
        for (int s = 0; s < 8; ++s) {
            float4 v = pv[s];
            bf16x4 pk = { (__bf16)v.x, (__bf16)v.y, (__bf16)v.z, (__bf16)v.w };
            int c4 = pf4[s] << 2;
            *(bf16x4*)&h_lds[1][prow[s] * HS + c4] = pk;
            *(bf16x4*)&h_tr[1][((c4 >> 4) << 10) + (prow[s] << 4) + (c4 & 15)] = pk;
        }
    }
    __syncthreads();

    // ================= P3: E=eGEMM+SM(b1) | P=PV(b0) =================
    if (w < 4) {
        egemm_softmax(h_lds[1], a_lds, adjv1, al_lds[1], inv_lds[1], w, l, g, g8);
    } else {
        pv_phase<8>(h_tr[0], al_lds[0], inv_lds[0],
                    out + b0 * NN * ND, w - 4, 0, l, g, g8);
    }
    __syncthreads();

    // ================= P4: all waves split PV(b1) =================
    pv_phase<4>(h_tr[1], al_lds[1], inv_lds[1],
                out + b1 * NN * ND, w & 3, (w >> 2) * 4, l, g, g8);
}

extern "C" void kernel_launch(void* const* d_in, const int* in_sizes, int n_in,
                              void* d_out, int out_size, void* d_ws, size_t ws_size,
                              hipStream_t stream) {
    const float* hidden = (const float*)d_in[0];
    const int*   adj    = (const int*)d_in[1];
    const float* a      = (const float*)d_in[2];
    float*       out    = (float*)d_out;
    gat_kernel<<<256, 512, 0, stream>>>(hidden, adj, a, out);
}

// Round 7
// 16.509 us; speedup vs baseline: 1.3253x; 1.3253x over previous
//
#include <hip/hip_runtime.h>
#include <hip/hip_bf16.h>

// B=512, N=64, D=128, 4 edge types.
// out[b] = softmax_j(select_k(leakyrelu((h*a_k) @ h^T), adj)) @ h
// R3 structure (best: 16.6us) + batched h-loads-first + setprio on MFMA.

#define NB 512
#define NN 64
#define ND 128
#define HS 136   // h_lds row stride (128 + 8 pad)
#define AS 72    // alpha row stride

typedef __bf16 bf16x8 __attribute__((ext_vector_type(8)));
typedef __bf16 bf16x4 __attribute__((ext_vector_type(4)));
typedef float  f32x4  __attribute__((ext_vector_type(4)));

__global__ __launch_bounds__(256)
void gat_kernel(const float* __restrict__ hidden,
                const int*   __restrict__ adj,
                const float* __restrict__ a,
                float*       __restrict__ out)
{
    __shared__ __bf16 h_lds[NN * HS];       // 17408 B  row-major, padded
    __shared__ __bf16 h_tr[8 * NN * 16];    // 16384 B  [dt][j][dcol] for tr-read
    __shared__ __bf16 al_lds[NN * AS];      //  9216 B  unnormalized exp(P)
    __shared__ float  a_lds[4 * ND];        //  2048 B
                                            //  total 45056 B

    const int t = threadIdx.x;
    const int l = t & 63;
    const int w = t >> 6;
    const int b = blockIdx.x;
    const int g  = l >> 4;              // 16-lane group 0..3
    const int g8 = g << 3;
    const int i0 = w * 16 + (g << 2);   // e-GEMM C/D row base

    // ---- h loads FIRST (critical path to the barrier): 8 float4 in flight ----
    const float4* hin = (const float4*)(hidden + (size_t)b * NN * ND);
    float4 sv[8];
    int srow[8], sc4[8];
    #pragma unroll
    for (int s = 0; s < 8; ++s) {
        srow[s] = ((l >> 2) & 15) | ((s >> 1) << 4);
        int f4  = (l & 3) | (w << 2) | ((s & 1) << 4);
        sc4[s]  = f4 << 2;
        sv[s] = hin[srow[s] * 32 + f4];
    }
    // ---- adj loads second (consumed after eGEMM; drain under compute) ----
    const int* adjb = adj + (size_t)b * NN * NN;
    int adjv[4][4];
    #pragma unroll
    for (int ct = 0; ct < 4; ++ct)
        #pragma unroll
        for (int r = 0; r < 4; ++r)
            adjv[ct][r] = adjb[(i0 + r) * NN + ct * 16 + (l & 15)];
    const float av0 = a[t];
    const float av1 = a[t + 256];

    // ---- LDS writes (wait only on the h loads) ----
    #pragma unroll
    for (int s = 0; s < 8; ++s) {
        float4 v = sv[s];
        bf16x4 pk = { (__bf16)v.x, (__bf16)v.y, (__bf16)v.z, (__bf16)v.w };
        *(bf16x4*)&h_lds[srow[s] * HS + sc4[s]] = pk;
        *(bf16x4*)&h_tr[((sc4[s] >> 4) << 10) + (srow[s] << 4) + (sc4[s] & 15)] = pk;
    }
    a_lds[t]       = av0;
    a_lds[t + 256] = av1;
    __syncthreads();   // the only barrier

    // ---- e-GEMM: e_k = (h*a_k) @ h^T ; wave w owns rows w*16..w*16+15 ----
    const int irow = w * 16 + (l & 15);
    f32x4 acc[4][4];   // [ct][k]
    #pragma unroll
    for (int ct = 0; ct < 4; ++ct)
        #pragma unroll
        for (int k = 0; k < 4; ++k)
            acc[ct][k] = (f32x4){0.f, 0.f, 0.f, 0.f};

    #pragma unroll
    for (int kk = 0; kk < 4; ++kk) {
        int d0 = kk * 32 + g8;
        bf16x8 hf = *(const bf16x8*)&h_lds[irow * HS + d0];
        float hff[8];
        #pragma unroll
        for (int e = 0; e < 8; ++e) hff[e] = (float)hf[e];
        bf16x8 hk[4];
        #pragma unroll
        for (int k = 0; k < 4; ++k) {
            float4 alo = *(const float4*)&a_lds[k * ND + d0];
            float4 ahi = *(const float4*)&a_lds[k * ND + d0 + 4];
            bf16x8 r;
            r[0] = (__bf16)(hff[0] * alo.x); r[1] = (__bf16)(hff[1] * alo.y);
            r[2] = (__bf16)(hff[2] * alo.z); r[3] = (__bf16)(hff[3] * alo.w);
            r[4] = (__bf16)(hff[4] * ahi.x); r[5] = (__bf16)(hff[5] * ahi.y);
            r[6] = (__bf16)(hff[6] * ahi.z); r[7] = (__bf16)(hff[7] * ahi.w);
            hk[k] = r;
        }
        bf16x8 bfr[4];
        #pragma unroll
        for (int ct = 0; ct < 4; ++ct)
            bfr[ct] = *(const bf16x8*)&h_lds[(ct * 16 + (l & 15)) * HS + d0];
        __builtin_amdgcn_s_setprio(1);
        #pragma unroll
        for (int ct = 0; ct < 4; ++ct)
            #pragma unroll
            for (int k = 0; k < 4; ++k)
                acc[ct][k] = __builtin_amdgcn_mfma_f32_16x16x32_bf16(hk[k], bfr[ct], acc[ct][k], 0, 0, 0);
        __builtin_amdgcn_s_setprio(0);
    }

    // ---- fused leakyrelu + adj-select (in registers) ----
    float sel[4][4];   // [ct][r]
    #pragma unroll
    for (int ct = 0; ct < 4; ++ct)
        #pragma unroll
        for (int r = 0; r < 4; ++r) {
            int av = adjv[ct][r];
            float e0 = fmaxf(acc[ct][0][r], 0.2f * acc[ct][0][r]);
            float e1 = fmaxf(acc[ct][1][r], 0.2f * acc[ct][1][r]);
            float e2 = fmaxf(acc[ct][2][r], 0.2f * acc[ct][2][r]);
            float e3 = fmaxf(acc[ct][3][r], 0.2f * acc[ct][3][r]);
            sel[ct][r] = av == 1 ? e0 : av == 2 ? e1 : av == 3 ? e2 : av == 4 ? e3 : -9.0e15f;
        }

    // ---- in-register softmax (row i0+r lives in this 16-lane group) ----
    float inv[4];
    #pragma unroll
    for (int r = 0; r < 4; ++r) {
        float m = fmaxf(fmaxf(sel[0][r], sel[1][r]), fmaxf(sel[2][r], sel[3][r]));
        m = fmaxf(m, __shfl_xor(m, 1));
        m = fmaxf(m, __shfl_xor(m, 2));
        m = fmaxf(m, __shfl_xor(m, 4));
        m = fmaxf(m, __shfl_xor(m, 8));
        float p0 = __expf(sel[0][r] - m);
        float p1 = __expf(sel[1][r] - m);
        float p2 = __expf(sel[2][r] - m);
        float p3 = __expf(sel[3][r] - m);
        float s = p0 + p1 + p2 + p3;
        s += __shfl_xor(s, 1);
        s += __shfl_xor(s, 2);
        s += __shfl_xor(s, 4);
        s += __shfl_xor(s, 8);
        inv[r] = 1.0f / s;
        int i = i0 + r;
        al_lds[i * AS +  0 + (l & 15)] = (__bf16)p0;   // unnormalized; scaled at store
        al_lds[i * AS + 16 + (l & 15)] = (__bf16)p1;
        al_lds[i * AS + 32 + (l & 15)] = (__bf16)p2;
        al_lds[i * AS + 48 + (l & 15)] = (__bf16)p3;
    }

    // ---- PV: out = diag(inv) * (P @ h); B-frags via hardware transpose read ----
    const int ia = w * 16 + (l & 15);
    bf16x8 aA0 = *(const bf16x8*)&al_lds[ia * AS + g8];
    bf16x8 aA1 = *(const bf16x8*)&al_lds[ia * AS + 32 + g8];
    float* outb = out + (size_t)b * NN * ND;
    unsigned trb = (unsigned)(unsigned long long)(&h_tr[0])
                 + (unsigned)(((l & 15) << 3) + (g << 8));
    #pragma unroll
    for (int dt = 0; dt < 8; ++dt) {
        unsigned ab = trb + dt * 2048;
        bf16x4 r0, r1, r2, r3;
        asm volatile("ds_read_b64_tr_b16 %0, %1"             : "=v"(r0) : "v"(ab));
        asm volatile("ds_read_b64_tr_b16 %0, %1 offset:128"  : "=v"(r1) : "v"(ab));
        asm volatile("ds_read_b64_tr_b16 %0, %1 offset:1024" : "=v"(r2) : "v"(ab));
        asm volatile("ds_read_b64_tr_b16 %0, %1 offset:1152" : "=v"(r3) : "v"(ab));
        asm volatile("s_waitcnt lgkmcnt(0)" ::: "memory");
        __builtin_amdgcn_sched_barrier(0);
        bf16x8 B0 = __builtin_shufflevector(r0, r1, 0, 1, 2, 3, 4, 5, 6, 7);
        bf16x8 B1 = __builtin_shufflevector(r2, r3, 0, 1, 2, 3, 4, 5, 6, 7);
        __builtin_amdgcn_s_setprio(1);
        f32x4 o = {0.f, 0.f, 0.f, 0.f};
        o = __builtin_amdgcn_mfma_f32_16x16x32_bf16(aA0, B0, o, 0, 0, 0);
        o = __builtin_amdgcn_mfma_f32_16x16x32_bf16(aA1, B1, o, 0, 0, 0);
        __builtin_amdgcn_s_setprio(0);
        int dr = dt * 16 + (l & 15);
        #pragma unroll
        for (int r = 0; r < 4; ++r)
            outb[(i0 + r) * ND + dr] = o[r] * inv[r];
    }
}

extern "C" void kernel_launch(void* const* d_in, const int* in_sizes, int n_in,
                              void* d_out, int out_size, void* d_ws, size_t ws_size,
                              hipStream_t stream) {
    const float* hidden = (const float*)d_in[0];
    const int*   adj    = (const int*)d_in[1];
    const float* a      = (const float*)d_in[2];
    float*       out    = (float*)d_out;
    gat_kernel<<<NB, 256, 0, stream>>>(hidden, adj, a, out);
}